// Round 13
// baseline (4298.496 us; speedup 1.0000x reference)
//
#include <hip/hip_runtime.h>
#include <stdint.h>

// ===================== Round 13 =====================
// Barrier dilution at constant supply. R10 data path (swapped GEMM1,
// pi-packed unswapped GEMM2, register-direct h) + ring-8 W LDS buffer
// (128KB) with ONE barrier per 4 chunks (vmcnt(0)+s_barrier+issue 4).
// GEMM2 un-lagged (h in regs, no LDS turnaround). xs deleted: eval-
// boundary transpose via 2.5KB/wave bounce reused 4x (per-ks-block);
// eval-0 X1 loaded from x0 directly in swapped layout.
// LDS 150.5K, regs ~230 (no spill), 256 blk x 8 waves.
// Predict: 1150-1500us, MfmaUtil 38-50, WRITE ~105KB, absmax 0.03125.
// Falsifier: >=1850us => barrier convoy not the serializer.
// ====================================================

typedef _Float16 half8 __attribute__((ext_vector_type(8)));
typedef float f32x4 __attribute__((ext_vector_type(4)));
typedef __attribute__((address_space(3))) char lchar;
typedef __attribute__((address_space(1))) char gchar;

static __device__ __forceinline__ void gload_lds16(const void* g, void* l) {
  __builtin_amdgcn_global_load_lds((const gchar*)g, (lchar*)l, 16, 0, 0);
}

static __device__ __forceinline__ unsigned short f2h(float x) {
  union { _Float16 h; unsigned short u; } cv;
  cv.h = (_Float16)x;
  return cv.u;
}
static __device__ __forceinline__ float h2f(unsigned short u) {
  union { unsigned short u; _Float16 h; } cv;
  cv.u = u;
  return (float)cv.h;
}
static __device__ __forceinline__ uint64_t pack4(float a, float b, float c, float d) {
  union { _Float16 h[4]; uint64_t q; } cv;
  cv.h[0] = (_Float16)a; cv.h[1] = (_Float16)b;
  cv.h[2] = (_Float16)c; cv.h[3] = (_Float16)d;
  return cv.q;
}

// Prepack (identical to R10): 16 chunks of 32 hid, chunk c at wp+c*16384:
//  [0,8K): W1T A-frags (swapped GEMM1), f = T*4+ks, natural k:
//          lane l holds A[m=hid c*32+T*16+(l&15)][k_in=ks*32+(l>>4)*8+j].
//  [8K,16K): W2 B-frags (unswapped GEMM2), f = 8+O, pi-permuted k:
//          lane l slot j holds B[k_hid=c*32+pi(g,j)][n=out O*16+(l&15)],
//          pi(g,j) = (j<4 ? 4g+j : 16+4g+(j-4)) -- matches GEMM1 C/D reg
//          order so h feeds GEMM2's A operand in registers.
__global__ void pack_w(const float* __restrict__ W1, const float* __restrict__ W2,
                       unsigned short* __restrict__ wp) {
  int id = blockIdx.x * 256 + threadIdx.x;  // 0..16383
  int lane = id & 63, fid = (id >> 6) & 255;
  int g = lane >> 4, lm = lane & 15;
  int c = fid >> 4, f = fid & 15;
  if (f < 8) {
    int T = f >> 2, ks = f & 3;
    int hid = c * 32 + T * 16 + lm;
#pragma unroll
    for (int j = 0; j < 8; ++j) {
      int kin = ks * 32 + g * 8 + j;
      wp[fid * 512 + lane * 8 + j] = f2h(W1[kin * 512 + hid]);
    }
  } else {
    int O = f - 8;
    int of = O * 16 + lm;
#pragma unroll
    for (int j = 0; j < 8; ++j) {
      int khl = (j < 4) ? (4 * g + j) : (16 + 4 * g + (j - 4));  // pi(g,j)
      wp[fid * 512 + lane * 8 + j] = f2h(W2[(c * 32 + khl) * 128 + of]);
    }
  }
}

__global__ __launch_bounds__(512, 2) void node_rk4(
    const float* __restrict__ x0, const float* __restrict__ b1,
    const float* __restrict__ b2, const unsigned short* __restrict__ wp,
    float* __restrict__ out) {
  // LDS: 128K W ring-8 + 20K bounce (8 waves x 32x40 halves) + 2K b1s.
  __shared__ char Wring[8][16384];
  __shared__ __align__(16) char bnc[8][2560];  // rows 80B (32x40 halves)
  __shared__ float b1s[512];

  const int tid = threadIdx.x;
  const int w = tid >> 6, lane = tid & 63;
  const int g = lane >> 4, lm = lane & 15;
  char* bw = bnc[w];

  b1s[tid] = b1[tid];
  float b2v[8];
#pragma unroll
  for (int O = 0; O < 8; ++O) b2v[O] = b2[O * 16 + lm];

  // UNSWAPPED state: lane (g,lm) holds batch rows mt*16+4g+j, feat col
  // O*16+lm. xa fp32 accumulator, xbh fp16 step base.
  const int rbase = blockIdx.x * 256 + w * 32;
  f32x4 xa[2][8];
  ushort4 xbh[2][8];
#pragma unroll
  for (int mt = 0; mt < 2; ++mt)
#pragma unroll
    for (int O = 0; O < 8; ++O) {
      f32x4 v;
#pragma unroll
      for (int j = 0; j < 4; ++j)
        v[j] = x0[(rbase + mt * 16 + 4 * g + j) * 128 + O * 16 + lm];
      xa[mt][O] = v;
      ushort4 hq;
      hq.x = f2h(v[0]); hq.y = f2h(v[1]); hq.z = f2h(v[2]); hq.w = f2h(v[3]);
      xbh[mt][O] = hq;
    }

  // Eval-0 X1 B-frags straight from x0 in swapped layout:
  // lane (g,lm): batch col rbase+nt*16+lm, k_in = ks*32+g*8+j.
  half8 X1[2][4];
#pragma unroll
  for (int nt = 0; nt < 2; ++nt)
#pragma unroll
    for (int ks = 0; ks < 4; ++ks) {
      const float* xr = &x0[(rbase + nt * 16 + lm) * 128 + ks * 32 + g * 8];
      f32x4 a = *(const f32x4*)xr;
      f32x4 b = *(const f32x4*)(xr + 4);
      union { uint64_t q[2]; half8 h; } u;
      u.q[0] = pack4(a[0], a[1], a[2], a[3]);
      u.q[1] = pack4(b[0], b[1], b[2], b[3]);
      X1[nt][ks] = u.h;
    }

  // Prologue: issue chunks 0..3 into ring slots 0..3 (2 gloads each: wave w
  // stages seg w of the W1 half and seg w of the W2 half).
#pragma unroll
  for (int pc = 0; pc < 4; ++pc) {
    const char* src = (const char*)wp + pc * 16384;
    gload_lds16(src + w * 1024 + lane * 16, Wring[pc] + w * 1024);
    gload_lds16(src + 8192 + w * 1024 + lane * 16, Wring[pc] + 8192 + w * 1024);
  }

#pragma unroll 1
  for (int it = 0; it < 80; ++it) {
    const int s = it & 3;
    const float wgt = (s == 0 || s == 3) ? (0.1f / 6.0f) : (0.1f / 3.0f);
    const float alph = (s < 2) ? 0.05f : 0.1f;

    f32x4 yacc[2][8];
#pragma unroll
    for (int mt = 0; mt < 2; ++mt)
#pragma unroll
      for (int O = 0; O < 8; ++O) yacc[mt][O] = f32x4{0.f, 0.f, 0.f, 0.f};

#pragma unroll
    for (int c = 0; c < 16; ++c) {
      if ((c & 3) == 0) {
        // Boundary: certify my 8 outstanding gloads (chunks c..c+3), then
        // block-wide publish; then issue chunks c+4..c+7 into slots
        // (c+4..c+7)&7 (overwriting chunks c-4..c-1, all reads < barrier).
        asm volatile("s_waitcnt vmcnt(0)" ::: "memory");
        __builtin_amdgcn_s_barrier();
#pragma unroll
        for (int d = 0; d < 4; ++d) {
          const int cn = (c + 4 + d) & 15;
          char* dst = Wring[(c + 4 + d) & 7];
          const char* src = (const char*)wp + cn * 16384;
          gload_lds16(src + w * 1024 + lane * 16, dst + w * 1024);
          gload_lds16(src + 8192 + w * 1024 + lane * 16, dst + 8192 + w * 1024);
        }
      }

      const char* Wb = Wring[c & 7];

      __builtin_amdgcn_s_setprio(1);
      // GEMM1'(c), swapped: h[hid][batch] = W1T(A, JIT LDS) x x^T(B regs).
      f32x4 hacc[2][2];  // [T][nt]
#pragma unroll
      for (int T = 0; T < 2; ++T)
#pragma unroll
        for (int nt = 0; nt < 2; ++nt) hacc[T][nt] = f32x4{0.f, 0.f, 0.f, 0.f};
#pragma unroll
      for (int T = 0; T < 2; ++T)
#pragma unroll
        for (int ks = 0; ks < 4; ++ks) {
          half8 wa = *(const half8*)(Wb + (T * 4 + ks) * 1024 + lane * 16);
          hacc[T][0] =
              __builtin_amdgcn_mfma_f32_16x16x32_f16(wa, X1[0][ks], hacc[T][0], 0, 0, 0);
          hacc[T][1] =
              __builtin_amdgcn_mfma_f32_16x16x32_f16(wa, X1[1][ks], hacc[T][1], 0, 0, 0);
        }
      __builtin_amdgcn_s_setprio(0);

      // bias+relu, pack into pi order [T0 j0..3 | T1 j0..3] -> hpk regs.
      f32x4 bb0 = *(const f32x4*)&b1s[c * 32 + 4 * g];
      f32x4 bb1 = *(const f32x4*)&b1s[c * 32 + 16 + 4 * g];
      half8 hpk0, hpk1;
      {
        union { uint64_t q[2]; half8 h; } u;
        u.q[0] = pack4(fmaxf(hacc[0][0][0] + bb0[0], 0.f),
                       fmaxf(hacc[0][0][1] + bb0[1], 0.f),
                       fmaxf(hacc[0][0][2] + bb0[2], 0.f),
                       fmaxf(hacc[0][0][3] + bb0[3], 0.f));
        u.q[1] = pack4(fmaxf(hacc[1][0][0] + bb1[0], 0.f),
                       fmaxf(hacc[1][0][1] + bb1[1], 0.f),
                       fmaxf(hacc[1][0][2] + bb1[2], 0.f),
                       fmaxf(hacc[1][0][3] + bb1[3], 0.f));
        hpk0 = u.h;
        u.q[0] = pack4(fmaxf(hacc[0][1][0] + bb0[0], 0.f),
                       fmaxf(hacc[0][1][1] + bb0[1], 0.f),
                       fmaxf(hacc[0][1][2] + bb0[2], 0.f),
                       fmaxf(hacc[0][1][3] + bb0[3], 0.f));
        u.q[1] = pack4(fmaxf(hacc[1][1][0] + bb1[0], 0.f),
                       fmaxf(hacc[1][1][1] + bb1[1], 0.f),
                       fmaxf(hacc[1][1][2] + bb1[2], 0.f),
                       fmaxf(hacc[1][1][3] + bb1[3], 0.f));
        hpk1 = u.h;
      }

      __builtin_amdgcn_s_setprio(1);
      // GEMM2(c), unswapped: y[batch][out] += h(A regs) x W2(B, JIT LDS).
#pragma unroll
      for (int O = 0; O < 8; ++O) {
        half8 w2f = *(const half8*)(Wb + 8192 + O * 1024 + lane * 16);
        yacc[0][O] = __builtin_amdgcn_mfma_f32_16x16x32_f16(hpk0, w2f, yacc[0][O], 0, 0, 0);
        yacc[1][O] = __builtin_amdgcn_mfma_f32_16x16x32_f16(hpk1, w2f, yacc[1][O], 0, 0, 0);
      }
      __builtin_amdgcn_s_setprio(0);
    }

    // RK4 combine. For it<79: per-ks-block bounce (write 32x32 sub-tile of
    // x_in, read 2 X1 frags back; wave-private 2.5KB buffer reused 4x).
    if (it < 79) {
#pragma unroll
      for (int ks = 0; ks < 4; ++ks) {
#pragma unroll
        for (int mt = 0; mt < 2; ++mt)
#pragma unroll
          for (int Oh = 0; Oh < 2; ++Oh) {
            const int O = 2 * ks + Oh;
            f32x4 k = yacc[mt][O];
#pragma unroll
            for (int j = 0; j < 4; ++j) k[j] += b2v[O];
            xa[mt][O] += wgt * k;
            ushort4 hq;
            if (s == 3) {
              f32x4 v = xa[mt][O];
              hq.x = f2h(v[0]); hq.y = f2h(v[1]); hq.z = f2h(v[2]); hq.w = f2h(v[3]);
              xbh[mt][O] = hq;
            } else {
              ushort4 xq = xbh[mt][O];
              hq.x = f2h(h2f(xq.x) + alph * k[0]);
              hq.y = f2h(h2f(xq.y) + alph * k[1]);
              hq.z = f2h(h2f(xq.z) + alph * k[2]);
              hq.w = f2h(h2f(xq.w) + alph * k[3]);
            }
            // bounce rows mt*16+4g+j, local col Oh*16+lm (80B rows)
            char* base = bw + (mt * 16 + 4 * g) * 80 + (Oh * 16 + lm) * 2;
            *(unsigned short*)(base) = hq.x;
            *(unsigned short*)(base + 80) = hq.y;
            *(unsigned short*)(base + 160) = hq.z;
            *(unsigned short*)(base + 240) = hq.w;
          }
        // read back next-eval X1 frags for this ks (rows nt*16+lm, col g*8)
#pragma unroll
        for (int nt = 0; nt < 2; ++nt)
          X1[nt][ks] = *(const half8*)(bw + (nt * 16 + lm) * 80 + g * 16);
      }
    } else {
      // last eval: only the fp32 accumulator update matters.
#pragma unroll
      for (int mt = 0; mt < 2; ++mt)
#pragma unroll
        for (int O = 0; O < 8; ++O) {
          f32x4 k = yacc[mt][O];
#pragma unroll
          for (int j = 0; j < 4; ++j) k[j] += b2v[O];
          xa[mt][O] += wgt * k;
        }
    }
  }

#pragma unroll
  for (int mt = 0; mt < 2; ++mt)
#pragma unroll
    for (int O = 0; O < 8; ++O)
#pragma unroll
      for (int j = 0; j < 4; ++j)
        out[(rbase + mt * 16 + 4 * g + j) * 128 + O * 16 + lm] = xa[mt][O][j];
}

extern "C" void kernel_launch(void* const* d_in, const int* in_sizes, int n_in,
                              void* d_out, int out_size, void* d_ws, size_t ws_size,
                              hipStream_t stream) {
  const float* x0 = (const float*)d_in[0];
  const float* W1 = (const float*)d_in[1];
  const float* b1 = (const float*)d_in[2];
  const float* W2 = (const float*)d_in[3];
  const float* b2 = (const float*)d_in[4];
  float* out = (float*)d_out;

  unsigned short* wp = (unsigned short*)d_ws;  // 256 frags * 1KB = 256KB

  pack_w<<<64, 256, 0, stream>>>(W1, W2, wp);
  node_rk4<<<256, 512, 0, stream>>>(x0, b1, b2, wp, out);
}